// Round 4
// baseline (48.170 us; speedup 1.0000x reference)
//
#include <hip/hip_runtime.h>

#define BATCH   256
#define NFEAT   20000
#define NVEC    (NFEAT / 4)
#define KSEL    256
#define NSAMP   8
#define CAP     4096

typedef unsigned long long u64;
typedef float __attribute__((ext_vector_type(4))) f32x4;   // clang-native for nontemporal stores

// Map float bits to unsigned key with same total order as float compare.
__device__ __forceinline__ unsigned fmap(float f) {
    unsigned u = __float_as_uint(f);
    return (u & 0x80000000u) ? ~u : (u | 0x80000000u);
}

// Wave 0 (64 lanes) scans hist[nbins-1 .. 0] top-down, finds bin where the
// cumulative count (from the top) reaches w. Writes bin -> *s_d and the
// remaining want inside that bin -> *s_w.
__device__ __forceinline__ void select_bin_wave0(const unsigned* hist, int nbins, int w,
                                                 int* s_d, int* s_w, int lane) {
    for (int base = nbins - 1; base >= 0; base -= 64) {
        int bin = base - lane;                       // lane 0 = highest bin
        unsigned c = (bin >= 0) ? hist[bin] : 0u;
        unsigned p = c;                              // inclusive scan from lane 0
#pragma unroll
        for (int off = 1; off < 64; off <<= 1) {
            unsigned t = __shfl_up(p, off);
            if (lane >= off) p += t;
        }
        unsigned long long m = __ballot(p >= (unsigned)w);
        if (m) {
            int l = __ffsll(m) - 1;                  // first lane (highest bin) crossing
            if (lane == l) { *s_d = bin; *s_w = w - (int)(p - c); }
            return;
        }
        w -= (int)__shfl(p, 63);                     // subtract whole-chunk sum
    }
    if (lane == 0) { *s_d = 0; *s_w = 1; }           // unreachable safety
}

// One 1024-thread block per row: exact top-K threshold as 64-bit composite
// (key<<32 | ~idx)  ->  element selected iff composite >= thr  (tie-break =
// lowest index, matching jax.lax.top_k). Then the SAME block writes the
// row's k-hot mask to all 8 sample slices (nontemporal, write-once data).
__global__ __launch_bounds__(1024) void topk_fused(const float* __restrict__ logits,
                                                   float* __restrict__ out) {
    const int b = blockIdx.x, tid = threadIdx.x;
    const int lane = tid & 63, wave = tid >> 6;
    const float4* row4 = (const float4*)(logits + (size_t)b * NFEAT);

    __shared__ unsigned hist[4096];
    __shared__ u64 cand[CAP];
    __shared__ int s_d, s_w;
    __shared__ unsigned s_cnt;
    __shared__ u64 s_thr;
    __shared__ int s_run, s_cut, s_wc[16];

    // ---- Pass 1: 12-bit histogram over key[31:20] ----
    for (int i = tid; i < 4096; i += 1024) hist[i] = 0;
    __syncthreads();
    for (int i = tid; i < NVEC; i += 1024) {
        float4 v = row4[i];
        atomicAdd(&hist[fmap(v.x) >> 20], 1u);
        atomicAdd(&hist[fmap(v.y) >> 20], 1u);
        atomicAdd(&hist[fmap(v.z) >> 20], 1u);
        atomicAdd(&hist[fmap(v.w) >> 20], 1u);
    }
    __syncthreads();
    if (wave == 0) select_bin_wave0(hist, 4096, KSEL, &s_d, &s_w, lane);
    __syncthreads();

    unsigned keypref = (unsigned)s_d;
    int w = s_w;
    int shift = 20;
    unsigned C;

    // ---- Pass 2: gather candidates matching key prefix (refine if overflow) ----
    for (;;) {
        if (tid == 0) s_cnt = 0;
        __syncthreads();
        for (int i = tid; i < NVEC; i += 1024) {
            float4 v = row4[i];
            const int base = i * 4;
            unsigned k;
            k = fmap(v.x); if ((k >> shift) == keypref) { unsigned p = atomicAdd(&s_cnt, 1u); if (p < CAP) cand[p] = ((u64)k << 32) | (unsigned)~(base + 0); }
            k = fmap(v.y); if ((k >> shift) == keypref) { unsigned p = atomicAdd(&s_cnt, 1u); if (p < CAP) cand[p] = ((u64)k << 32) | (unsigned)~(base + 1); }
            k = fmap(v.z); if ((k >> shift) == keypref) { unsigned p = atomicAdd(&s_cnt, 1u); if (p < CAP) cand[p] = ((u64)k << 32) | (unsigned)~(base + 2); }
            k = fmap(v.w); if ((k >> shift) == keypref) { unsigned p = atomicAdd(&s_cnt, 1u); if (p < CAP) cand[p] = ((u64)k << 32) | (unsigned)~(base + 3); }
        }
        __syncthreads();
        C = s_cnt;
        if (C <= CAP || shift == 0) break;

        // overflow (unreachable for this input): refine key prefix by 12/8 bits
        const int nb = (shift >= 12) ? 12 : shift;
        const int nsh = shift - nb;
        const unsigned mask = (1u << nb) - 1u;
        for (int i = tid; i < (1 << nb); i += 1024) hist[i] = 0;
        __syncthreads();
        for (int i = tid; i < NVEC; i += 1024) {
            float4 v = row4[i];
            unsigned k;
            k = fmap(v.x); if ((k >> shift) == keypref) atomicAdd(&hist[(k >> nsh) & mask], 1u);
            k = fmap(v.y); if ((k >> shift) == keypref) atomicAdd(&hist[(k >> nsh) & mask], 1u);
            k = fmap(v.z); if ((k >> shift) == keypref) atomicAdd(&hist[(k >> nsh) & mask], 1u);
            k = fmap(v.w); if ((k >> shift) == keypref) atomicAdd(&hist[(k >> nsh) & mask], 1u);
        }
        __syncthreads();
        if (wave == 0) select_bin_wave0(hist, 1 << nb, w, &s_d, &s_w, lane);
        __syncthreads();
        keypref = (keypref << nb) | (unsigned)s_d;
        w = s_w;
        shift = nsh;
    }

    if (C <= CAP) {
        // ---- In-LDS radix select: w-th largest composite among C candidates ----
        u64 pfx = keypref;
        int pshift = 32 + shift;       // candidates share composite >> pshift == pfx
        bool done = false;
        while (!done) {
            const int nb = (pshift >= 8) ? 8 : pshift;
            const int nsh = pshift - nb;
            const unsigned mask = (1u << nb) - 1u;
            for (int i = tid; i < (1 << nb); i += 1024) hist[i] = 0;
            __syncthreads();
            for (int i = tid; i < (int)C; i += 1024) {
                u64 c = cand[i];
                if ((c >> pshift) == pfx) atomicAdd(&hist[(unsigned)(c >> nsh) & mask], 1u);
            }
            __syncthreads();
            if (wave == 0) select_bin_wave0(hist, 1 << nb, w, &s_d, &s_w, lane);
            __syncthreads();
            const unsigned cnt = hist[s_d];
            pfx = (pfx << nb) | (unsigned)s_d;
            w = s_w;
            pshift = nsh;
            if (cnt == 1u || pshift == 0) {
                if (cnt == 1u && pshift > 0) {
                    for (int i = tid; i < (int)C; i += 1024) {
                        u64 c = cand[i];
                        if ((c >> pshift) == pfx) s_thr = c;   // exactly one writer
                    }
                } else if (tid == 0) {
                    s_thr = pfx;                               // fully resolved
                }
                done = true;
            }
            __syncthreads();
        }
    } else {
        // shift==0, full key resolved, >CAP exact duplicates (unreachable):
        // find w-th smallest index among exact-key matches via ordered ballot scan.
        if (tid == 0) { s_run = 0; s_cut = 0; }
        __syncthreads();
        const float* row = logits + (size_t)b * NFEAT;
        for (int base = 0; base < NFEAT; base += 1024) {
            const int i = base + tid;
            const bool eq = (i < NFEAT) && (fmap(row[i]) == keypref);
            const unsigned long long bal = __ballot(eq);
            if (lane == 0) s_wc[wave] = __popcll(bal);
            __syncthreads();
            int off = s_run;
            for (int x = 0; x < wave; ++x) off += s_wc[x];
            const int rank = off + __popcll(bal & ((lane == 0) ? 0ull : ((1ull << lane) - 1ull)));
            if (eq && rank == w - 1) s_cut = i;
            __syncthreads();
            if (tid == 0) { int t = 0; for (int x = 0; x < 16; ++x) t += s_wc[x]; s_run += t; }
            __syncthreads();
            if (s_run >= w) break;
        }
        if (tid == 0) s_thr = ((u64)keypref << 32) | (unsigned)~s_cut;
        __syncthreads();
    }

    __syncthreads();
    const u64 thr = s_thr;

    // ---- Phase B: write k-hot mask for this row to all 8 sample slices ----
    float* outrow = out + (size_t)b * NFEAT;
    for (int i = tid; i < NVEC; i += 1024) {
        const int n = i * 4;
        const float4 v = row4[i];
        f32x4 m;
        {
            const float* vf = &v.x;
            m.x = (((u64)fmap(vf[0]) << 32) | (unsigned)~(n + 0)) >= thr ? 1.0f : 0.0f;
            m.y = (((u64)fmap(vf[1]) << 32) | (unsigned)~(n + 1)) >= thr ? 1.0f : 0.0f;
            m.z = (((u64)fmap(vf[2]) << 32) | (unsigned)~(n + 2)) >= thr ? 1.0f : 0.0f;
            m.w = (((u64)fmap(vf[3]) << 32) | (unsigned)~(n + 3)) >= thr ? 1.0f : 0.0f;
        }
#pragma unroll
        for (int s = 0; s < NSAMP; ++s) {
            f32x4* dst = reinterpret_cast<f32x4*>(outrow + (size_t)s * BATCH * NFEAT + n);
            __builtin_nontemporal_store(m, dst);
        }
    }
}

extern "C" void kernel_launch(void* const* d_in, const int* in_sizes, int n_in,
                              void* d_out, int out_size, void* d_ws, size_t ws_size,
                              hipStream_t stream) {
    const float* logits = (const float*)d_in[0];
    float* out = (float*)d_out;
    (void)d_ws; (void)ws_size;

    topk_fused<<<BATCH, 1024, 0, stream>>>(logits, out);
}

// Round 5
// 42.445 us; speedup vs baseline: 1.1349x; 1.1349x over previous
//
#include <hip/hip_runtime.h>

#define BATCH   256
#define NFEAT   20000
#define NVEC    (NFEAT / 4)
#define KSEL    256
#define NSAMP   8
#define CAP     2048
#define RANKC   512

typedef unsigned long long u64;
typedef float    __attribute__((ext_vector_type(4))) f32x4;
typedef unsigned __attribute__((ext_vector_type(4))) u32x4;

// Map float bits to unsigned key with same total order as float compare.
__device__ __forceinline__ unsigned fmap(float f) {
    unsigned u = __float_as_uint(f);
    return (u & 0x80000000u) ? ~u : (u | 0x80000000u);
}

// Generic top-down bin pick by wave 0 (only used on rare refine paths).
__device__ __forceinline__ void select_bin_wave0(const unsigned* hist, int nbins, int w,
                                                 int* s_d, int* s_w, int lane) {
    for (int base = nbins - 1; base >= 0; base -= 64) {
        int bin = base - lane;
        unsigned c = (bin >= 0) ? hist[bin] : 0u;
        unsigned p = c;
#pragma unroll
        for (int off = 1; off < 64; off <<= 1) {
            unsigned t = __shfl_up(p, off);
            if (lane >= off) p += t;
        }
        unsigned long long m = __ballot(p >= (unsigned)w);
        if (m) {
            int l = __ffsll(m) - 1;
            if (lane == l) { *s_d = bin; *s_w = w - (int)(p - c); }
            return;
        }
        w -= (int)__shfl(p, 63);
    }
    if (lane == 0) { *s_d = 0; *s_w = 1; }
}

// Fast pick over exactly 64 entries (arr[63] = highest bin), wave 0 only.
__device__ __forceinline__ void pick64(const unsigned* arr, int w, int lane,
                                       int* s_idx, int* s_w) {
    unsigned c = arr[63 - lane];
    unsigned p = c;
#pragma unroll
    for (int off = 1; off < 64; off <<= 1) {
        unsigned t = __shfl_up(p, off);
        if (lane >= off) p += t;
    }
    unsigned long long m = __ballot(p >= (unsigned)w);
    if (m) {
        int l = __ffsll(m) - 1;
        if (lane == l) { *s_idx = 63 - l; *s_w = w - (int)(p - c); }
    } else if (lane == 0) { *s_idx = 0; *s_w = 1; }   // unreachable safety
}

// One 1024-thread block per row. Keys staged in LDS; one global read of the
// row total. Exact top-K threshold as 64-bit composite (key<<32 | ~idx):
// selected iff composite >= thr (tie-break = lowest index, = jax.lax.top_k).
// Same block then streams the k-hot mask to all 8 sample slices.
__global__ __launch_bounds__(1024) void topk_fused(const float* __restrict__ logits,
                                                   float* __restrict__ out) {
    const int b = blockIdx.x, tid = threadIdx.x;
    const int lane = tid & 63, wave = tid >> 6;
    const float4* __restrict__ row4 = (const float4*)(logits + (size_t)b * NFEAT);

    __shared__ __align__(16) unsigned key[NFEAT];   // 80000 B
    __shared__ unsigned hist[4096];                 // 16384 B
    __shared__ u64 candA[CAP];                      // 16384 B
    __shared__ u64 candB[CAP];                      // 16384 B
    __shared__ unsigned csum[64];
    __shared__ int s_d, s_w;
    __shared__ unsigned s_cnt;
    __shared__ u64 s_thr;
    __shared__ int s_run, s_cut, s_wc[16];

    u32x4* key4 = (u32x4*)key;

    // ---- Phase 1: one global pass — keys -> LDS + 12-bit histogram ----
    for (int i = tid; i < 4096; i += 1024) hist[i] = 0;
    __syncthreads();
    for (int i = tid; i < NVEC; i += 1024) {
        float4 v = row4[i];
        unsigned k0 = fmap(v.x), k1 = fmap(v.y), k2 = fmap(v.z), k3 = fmap(v.w);
        u32x4 kv; kv.x = k0; kv.y = k1; kv.z = k2; kv.w = k3;
        key4[i] = kv;
        atomicAdd(&hist[k0 >> 20], 1u);
        atomicAdd(&hist[k1 >> 20], 1u);
        atomicAdd(&hist[k2 >> 20], 1u);
        atomicAdd(&hist[k3 >> 20], 1u);
    }
    __syncthreads();

    // ---- Phase 2: hierarchical threshold-bin pick (parallel chunk sums) ----
    unsigned keypref; int w; int shift = 20;
    {
#pragma unroll
        for (int j = 0; j < 4; ++j) {
            const int c = wave * 4 + j;
            unsigned v = hist[c * 64 + lane];
#pragma unroll
            for (int off = 32; off; off >>= 1) v += __shfl_down(v, off);
            if (lane == 0) csum[c] = v;
        }
        __syncthreads();
        if (wave == 0) pick64(csum, KSEL, lane, &s_d, &s_w);
        __syncthreads();
        const int chunk = s_d; const int w0 = s_w;
        if (wave == 0) pick64(&hist[chunk * 64], w0, lane, &s_d, &s_w);
        __syncthreads();
        keypref = (unsigned)(chunk * 64 + s_d);
        w = s_w;
    }
    unsigned cnt = hist[keypref];
    __syncthreads();

    // ---- rare: refine key prefix from LDS keys until candidate set fits ----
    while (cnt > CAP && shift > 0) {
        const int nb = (shift >= 12) ? 12 : shift;
        const int nsh = shift - nb;
        const unsigned mask = (1u << nb) - 1u;
        for (int i = tid; i < (1 << nb); i += 1024) hist[i] = 0;
        __syncthreads();
        for (int i = tid; i < NFEAT; i += 1024) {
            unsigned k = key[i];
            if ((k >> shift) == keypref) atomicAdd(&hist[(k >> nsh) & mask], 1u);
        }
        __syncthreads();
        if (wave == 0) select_bin_wave0(hist, 1 << nb, w, &s_d, &s_w, lane);
        __syncthreads();
        keypref = (keypref << nb) | (unsigned)s_d;
        w = s_w;
        shift = nsh;
        cnt = hist[s_d];
        __syncthreads();
    }

    // ---- Phase 3: gather candidate composites from LDS keys ----
    if (tid == 0) s_cnt = 0;
    __syncthreads();
    for (int i = tid; i < NFEAT; i += 1024) {
        unsigned k = key[i];
        if ((k >> shift) == keypref) {
            unsigned p = atomicAdd(&s_cnt, 1u);
            if (p < CAP) candA[p] = ((u64)k << 32) | (unsigned)~i;
        }
    }
    __syncthreads();
    unsigned C = s_cnt;

    if (C <= CAP) {
        // rare: shrink candidate set by composite-prefix refine (ping-pong)
        u64* src = candA; u64* dst = candB;
        int pshift = 32 + shift;
        while (C > RANKC && pshift > 0) {
            const int nb = (pshift >= 12) ? 12 : pshift;
            const int nsh = pshift - nb;
            const unsigned mask = (1u << nb) - 1u;
            for (int i = tid; i < (1 << nb); i += 1024) hist[i] = 0;
            __syncthreads();
            for (int i = tid; i < (int)C; i += 1024)
                atomicAdd(&hist[(unsigned)(src[i] >> nsh) & mask], 1u);
            __syncthreads();
            if (wave == 0) select_bin_wave0(hist, 1 << nb, w, &s_d, &s_w, lane);
            __syncthreads();
            const unsigned d = (unsigned)s_d;
            w = s_w;
            if (tid == 0) s_cnt = 0;
            __syncthreads();
            for (int i = tid; i < (int)C; i += 1024) {
                u64 c = src[i];
                if (((unsigned)(c >> nsh) & mask) == d) {
                    unsigned p = atomicAdd(&s_cnt, 1u);
                    dst[p] = c;
                }
            }
            __syncthreads();
            C = s_cnt;
            pshift = nsh;
            u64* t = src; src = dst; dst = t;
            __syncthreads();
        }
        // ---- Phase 4: ranking select — w-th largest has exactly w-1 greater ----
        for (int i = tid; i < (int)C; i += 1024) {
            u64 ci = src[i];
            int cgt = 0;
            for (int j = 0; j < (int)C; ++j) cgt += (src[j] > ci) ? 1 : 0;
            if (cgt == w - 1) s_thr = ci;   // exactly one writer (all distinct)
        }
        __syncthreads();
    } else {
        // unreachable in practice: >CAP exact-duplicate keys (shift==0).
        // Ordered ballot scan over LDS keys for w-th smallest matching index.
        if (tid == 0) { s_run = 0; s_cut = 0; }
        __syncthreads();
        for (int base = 0; base < NFEAT; base += 1024) {
            const int i = base + tid;
            const bool eq = (i < NFEAT) && (key[i] == keypref);
            const unsigned long long bal = __ballot(eq);
            if (lane == 0) s_wc[wave] = __popcll(bal);
            __syncthreads();
            int off = s_run;
            for (int x = 0; x < wave; ++x) off += s_wc[x];
            const int rank = off + __popcll(bal & ((lane == 0) ? 0ull : ((1ull << lane) - 1ull)));
            if (eq && rank == w - 1) s_cut = i;
            __syncthreads();
            if (tid == 0) { int t = 0; for (int x = 0; x < 16; ++x) t += s_wc[x]; s_run += t; }
            __syncthreads();
            if (s_run >= w) break;
        }
        if (tid == 0) s_thr = ((u64)keypref << 32) | (unsigned)~s_cut;
        __syncthreads();
    }

    // ---- Phase 5: stream k-hot mask from LDS keys to all 8 sample slices ----
    const u64 thr = s_thr;
    const size_t rowoff = (size_t)b * NFEAT;
    for (int i = tid; i < NVEC; i += 1024) {
        const u32x4 k = key4[i];
        const int n = i * 4;
        f32x4 m;
        m.x = ((((u64)k.x << 32) | (unsigned)~(n + 0)) >= thr) ? 1.0f : 0.0f;
        m.y = ((((u64)k.y << 32) | (unsigned)~(n + 1)) >= thr) ? 1.0f : 0.0f;
        m.z = ((((u64)k.z << 32) | (unsigned)~(n + 2)) >= thr) ? 1.0f : 0.0f;
        m.w = ((((u64)k.w << 32) | (unsigned)~(n + 3)) >= thr) ? 1.0f : 0.0f;
#pragma unroll
        for (int s = 0; s < NSAMP; ++s) {
            *reinterpret_cast<f32x4*>(out + (size_t)s * BATCH * NFEAT + rowoff + n) = m;
        }
    }
}

extern "C" void kernel_launch(void* const* d_in, const int* in_sizes, int n_in,
                              void* d_out, int out_size, void* d_ws, size_t ws_size,
                              hipStream_t stream) {
    const float* logits = (const float*)d_in[0];
    float* out = (float*)d_out;
    (void)d_ws; (void)ws_size;

    topk_fused<<<BATCH, 1024, 0, stream>>>(logits, out);
}

// Round 6
// 36.629 us; speedup vs baseline: 1.3151x; 1.1588x over previous
//
#include <hip/hip_runtime.h>

#define BATCH   256
#define NFEAT   20000
#define NVEC    (NFEAT / 4)
#define KSEL    256
#define NSAMP   8
#define CAP     2048

typedef unsigned long long u64;
typedef float __attribute__((ext_vector_type(4))) f32x4;

// Map float bits to unsigned key with same total order as float compare.
__device__ __forceinline__ unsigned fmap(float f) {
    unsigned u = __float_as_uint(f);
    return (u & 0x80000000u) ? ~u : (u | 0x80000000u);
}

// Generic top-down bin pick by wave 0 (rare refine path only).
__device__ __forceinline__ void select_bin_wave0(const unsigned* hist, int nbins, int w,
                                                 int* s_d, int* s_w, int lane) {
    for (int base = nbins - 1; base >= 0; base -= 64) {
        int bin = base - lane;
        unsigned c = (bin >= 0) ? hist[bin] : 0u;
        unsigned p = c;
#pragma unroll
        for (int off = 1; off < 64; off <<= 1) {
            unsigned t = __shfl_up(p, off);
            if (lane >= off) p += t;
        }
        unsigned long long m = __ballot(p >= (unsigned)w);
        if (m) {
            int l = __ffsll(m) - 1;
            if (lane == l) { *s_d = bin; *s_w = w - (int)(p - c); }
            return;
        }
        w -= (int)__shfl(p, 63);
    }
    if (lane == 0) { *s_d = 0; *s_w = 1; }
}

// Fast pick over exactly 64 entries (arr[63] = highest bin), wave 0 only.
__device__ __forceinline__ void pick64(const unsigned* arr, int w, int lane,
                                       int* s_idx, int* s_w) {
    unsigned c = arr[63 - lane];
    unsigned p = c;
#pragma unroll
    for (int off = 1; off < 64; off <<= 1) {
        unsigned t = __shfl_up(p, off);
        if (lane >= off) p += t;
    }
    unsigned long long m = __ballot(p >= (unsigned)w);
    if (m) {
        int l = __ffsll(m) - 1;
        if (lane == l) { *s_idx = 63 - l; *s_w = w - (int)(p - c); }
    } else if (lane == 0) { *s_idx = 0; *s_w = 1; }
}

// One 1024-thread block per row; row held in registers (20 keys/thread).
// Exact top-K threshold as 64-bit composite (key<<32 | ~idx): selected iff
// composite >= thr (tie-break = lowest index, matching jax.lax.top_k).
// Same block then streams the k-hot mask to all 8 sample slices.
__global__ __launch_bounds__(1024) void topk_fused(const float* __restrict__ logits,
                                                   float* __restrict__ out) {
    const int b = blockIdx.x, tid = threadIdx.x;
    const int lane = tid & 63, wave = tid >> 6;
    const float4* __restrict__ row4 = (const float4*)(logits + (size_t)b * NFEAT);

    __shared__ unsigned hist[4096];     // 16 KB
    __shared__ u64 cand[CAP];           // 16 KB
    __shared__ unsigned csum[64];
    __shared__ int s_d, s_w;
    __shared__ unsigned s_cnt;
    __shared__ u64 s_thr;
    __shared__ int s_run, s_cut, s_wc[16];

    // ---- Phase 1: issue 5 independent global loads early ----
    float4 v[5];
#pragma unroll
    for (int j = 0; j < 5; ++j) {
        const int i4 = tid + j * 1024;
        v[j] = row4[(i4 < NVEC) ? i4 : (NVEC - 1)];
    }
    // zero hist while loads are in flight
#pragma unroll
    for (int j = 0; j < 4; ++j) hist[tid + j * 1024] = 0;
    __syncthreads();

    unsigned kk[5][4];
#pragma unroll
    for (int j = 0; j < 5; ++j) {
        kk[j][0] = fmap(v[j].x); kk[j][1] = fmap(v[j].y);
        kk[j][2] = fmap(v[j].z); kk[j][3] = fmap(v[j].w);
    }
#pragma unroll
    for (int j = 0; j < 4; ++j) {
#pragma unroll
        for (int e = 0; e < 4; ++e) atomicAdd(&hist[kk[j][e] >> 20], 1u);
    }
    if (tid + 4096 < NVEC) {
#pragma unroll
        for (int e = 0; e < 4; ++e) atomicAdd(&hist[kk[4][e] >> 20], 1u);
    }
    __syncthreads();

    // ---- Phase 2: hierarchical threshold-bin pick ----
    unsigned keypref; int w;
    {
#pragma unroll
        for (int j = 0; j < 4; ++j) {
            const int c = wave * 4 + j;
            unsigned x = hist[c * 64 + lane];
#pragma unroll
            for (int off = 32; off; off >>= 1) x += __shfl_down(x, off);
            if (lane == 0) csum[c] = x;
        }
        __syncthreads();
        if (wave == 0) pick64(csum, KSEL, lane, &s_d, &s_w);
        __syncthreads();
        const int chunk = s_d; const int w0 = s_w;
        if (wave == 0) pick64(&hist[chunk * 64], w0, lane, &s_d, &s_w);
        if (tid == 0) s_cnt = 0;
        __syncthreads();
        keypref = (unsigned)(chunk * 64 + s_d);
        w = s_w;
    }
    int shift = 20;

    // ---- Phase 3: gather candidate composites from registers ----
    unsigned C;
    for (;;) {
#pragma unroll
        for (int j = 0; j < 5; ++j) {
            const int i4 = tid + j * 1024;
            if (i4 < NVEC) {
#pragma unroll
                for (int e = 0; e < 4; ++e) {
                    const unsigned k = kk[j][e];
                    if ((k >> shift) == keypref) {
                        unsigned p = atomicAdd(&s_cnt, 1u);
                        if (p < CAP) cand[p] = ((u64)k << 32) | (unsigned)~(4 * i4 + e);
                    }
                }
            }
        }
        __syncthreads();
        C = s_cnt;
        if (C <= CAP || shift == 0) break;

        // rare: refine key prefix from reg keys until candidate set fits
        const int nb = (shift >= 12) ? 12 : shift;
        const int nsh = shift - nb;
        for (int i = tid; i < (1 << nb); i += 1024) hist[i] = 0;
        __syncthreads();
#pragma unroll
        for (int j = 0; j < 5; ++j) {
            const int i4 = tid + j * 1024;
            if (i4 < NVEC) {
#pragma unroll
                for (int e = 0; e < 4; ++e) {
                    const unsigned k = kk[j][e];
                    if ((k >> shift) == keypref)
                        atomicAdd(&hist[(k >> nsh) & ((1u << nb) - 1u)], 1u);
                }
            }
        }
        __syncthreads();
        if (wave == 0) select_bin_wave0(hist, 1 << nb, w, &s_d, &s_w, lane);
        if (tid == 0) s_cnt = 0;
        __syncthreads();
        keypref = (keypref << nb) | (unsigned)s_d;
        w = s_w;
        shift = nsh;
    }

    // ---- Phase 4: resolve exact threshold ----
    if (C <= CAP) {
        // ranking select: the w-th largest has exactly w-1 greater (all distinct)
        for (int i = tid; i < (int)C; i += 1024) {
            const u64 ci = cand[i];
            int cgt = 0;
            for (int j = 0; j < (int)C; ++j) cgt += (cand[j] > ci) ? 1 : 0;
            if (cgt == w - 1) s_thr = ci;
        }
        __syncthreads();
    } else {
        // unreachable in practice: shift==0 with >CAP exact-duplicate keys.
        // Ordered rank over reg keys for the w-th smallest matching index.
        if (tid == 0) { s_run = 0; s_cut = 0; }
        __syncthreads();
#pragma unroll 1
        for (int j = 0; j < 5; ++j) {
            const int i4 = tid + j * 1024;
            bool eq[4];
            int cnt4 = 0;
#pragma unroll
            for (int e = 0; e < 4; ++e) {
                eq[e] = (i4 < NVEC) && (kk[j][e] == keypref);
                cnt4 += eq[e] ? 1 : 0;
            }
            unsigned p = (unsigned)cnt4;
#pragma unroll
            for (int off = 1; off < 64; off <<= 1) {
                unsigned t = __shfl_up(p, off);
                if (lane >= off) p += t;
            }
            const unsigned excl = p - (unsigned)cnt4;
            if (lane == 63) s_wc[wave] = (int)p;
            __syncthreads();
            int off0 = s_run + (int)excl;
            for (int x = 0; x < wave; ++x) off0 += s_wc[x];
#pragma unroll
            for (int e = 0; e < 4; ++e) {
                if (eq[e]) { if (off0 == w - 1) s_cut = 4 * i4 + e; ++off0; }
            }
            __syncthreads();
            if (tid == 0) { int t = 0; for (int x = 0; x < 16; ++x) t += s_wc[x]; s_run += t; }
            __syncthreads();
            if (s_run >= w) break;
        }
        if (tid == 0) s_thr = ((u64)keypref << 32) | (unsigned)~s_cut;
        __syncthreads();
    }

    // ---- Phase 5: stream k-hot mask from registers to all 8 sample slices ----
    const u64 thr = s_thr;
    const unsigned thr_k = (unsigned)(thr >> 32);
    const unsigned thr_l = (unsigned)thr;
    float* const outb = out + (size_t)b * NFEAT;
#pragma unroll
    for (int j = 0; j < 5; ++j) {
        const int i4 = tid + j * 1024;
        if (i4 < NVEC) {
            const int n = 4 * i4;
            f32x4 m;
#pragma unroll
            for (int e = 0; e < 4; ++e) {
                const unsigned k = kk[j][e];
                const bool sel = (k > thr_k) || (k == thr_k && (unsigned)~(n + e) >= thr_l);
                m[e] = sel ? 1.0f : 0.0f;
            }
#pragma unroll
            for (int s = 0; s < NSAMP; ++s) {
                *reinterpret_cast<f32x4*>(outb + (size_t)s * ((size_t)BATCH * NFEAT) + n) = m;
            }
        }
    }
}

extern "C" void kernel_launch(void* const* d_in, const int* in_sizes, int n_in,
                              void* d_out, int out_size, void* d_ws, size_t ws_size,
                              hipStream_t stream) {
    const float* logits = (const float*)d_in[0];
    float* out = (float*)d_out;
    (void)d_ws; (void)ws_size;

    topk_fused<<<BATCH, 1024, 0, stream>>>(logits, out);
}

// Round 7
// 34.640 us; speedup vs baseline: 1.3906x; 1.0574x over previous
//
#include <hip/hip_runtime.h>

#define BATCH   256
#define NFEAT   20000
#define NVEC    (NFEAT / 4)
#define KSEL    256
#define NSAMP   8
#define CAP     2048

typedef unsigned long long u64;
typedef float __attribute__((ext_vector_type(4))) f32x4;

// Raw barrier: orders LDS (lgkmcnt) but does NOT drain vmcnt — zero-stores
// stay in flight across select-phase barriers. All cross-wave communication
// in this kernel is LDS-only, so lgkmcnt(0) + s_barrier is sufficient.
#define BAR() do { asm volatile("s_waitcnt lgkmcnt(0)" ::: "memory"); \
                   __builtin_amdgcn_s_barrier();                      \
                   asm volatile("" ::: "memory"); } while (0)

// Map float bits to unsigned key with same total order as float compare.
__device__ __forceinline__ unsigned fmap(float f) {
    unsigned u = __float_as_uint(f);
    return (u & 0x80000000u) ? ~u : (u | 0x80000000u);
}

// Generic top-down bin pick by wave 0 (rare refine path only).
__device__ __forceinline__ void select_bin_wave0(const unsigned* hist, int nbins, int w,
                                                 int* s_d, int* s_w, int lane) {
    for (int base = nbins - 1; base >= 0; base -= 64) {
        int bin = base - lane;
        unsigned c = (bin >= 0) ? hist[bin] : 0u;
        unsigned p = c;
#pragma unroll
        for (int off = 1; off < 64; off <<= 1) {
            unsigned t = __shfl_up(p, off);
            if (lane >= off) p += t;
        }
        unsigned long long m = __ballot(p >= (unsigned)w);
        if (m) {
            int l = __ffsll(m) - 1;
            if (lane == l) { *s_d = bin; *s_w = w - (int)(p - c); }
            return;
        }
        w -= (int)__shfl(p, 63);
    }
    if (lane == 0) { *s_d = 0; *s_w = 1; }
}

// Fast pick over exactly 64 entries (arr[63] = highest bin), wave 0 only.
__device__ __forceinline__ void pick64(const unsigned* arr, int w, int lane,
                                       int* s_idx, int* s_w) {
    unsigned c = arr[63 - lane];
    unsigned p = c;
#pragma unroll
    for (int off = 1; off < 64; off <<= 1) {
        unsigned t = __shfl_up(p, off);
        if (lane >= off) p += t;
    }
    unsigned long long m = __ballot(p >= (unsigned)w);
    if (m) {
        int l = __ffsll(m) - 1;
        if (lane == l) { *s_idx = 63 - l; *s_w = w - (int)(p - c); }
    } else if (lane == 0) { *s_idx = 0; *s_w = 1; }
}

// One 1024-thread block per row; row held in registers (20 keys/thread).
// Zero-stores for the entire output row (all 8 slices) are ISSUED during the
// select phases and drain at HBM rate while the select runs; after the exact
// top-K threshold (64-bit composite key<<32 | ~idx, tie-break = lowest index
// = jax.lax.top_k) is known, vmcnt(0) + each thread rewrites its own selected
// elements with 1.0 (same-thread same-address => ordered after the drain).
__global__ __launch_bounds__(1024) void topk_fused(const float* __restrict__ logits,
                                                   float* __restrict__ out) {
    const int b = blockIdx.x, tid = threadIdx.x;
    const int lane = tid & 63, wave = tid >> 6;
    const float4* __restrict__ row4 = (const float4*)(logits + (size_t)b * NFEAT);
    const size_t BN = (size_t)BATCH * NFEAT;
    float* const outb = out + (size_t)b * NFEAT;
    const f32x4 z4 = {0.0f, 0.0f, 0.0f, 0.0f};

#define ZSTORE(J)                                                              \
    do {                                                                       \
        const int i4_ = tid + (J) * 1024;                                      \
        if (i4_ < NVEC) {                                                      \
            _Pragma("unroll")                                                  \
            for (int s_ = 0; s_ < NSAMP; ++s_)                                 \
                *reinterpret_cast<f32x4*>(outb + (size_t)s_ * BN + 4 * i4_) = z4; \
        }                                                                      \
    } while (0)

    __shared__ unsigned hist[4096];     // 16 KB
    __shared__ u64 cand[CAP];           // 16 KB
    __shared__ unsigned csum[64];
    __shared__ int s_d, s_w;
    __shared__ unsigned s_cnt;
    __shared__ u64 s_thr;
    __shared__ int s_run, s_cut, s_wc[16];

    // ---- Phase 1: issue row loads, then zero-stores chunks 0-1 ----
    float4 v[5];
#pragma unroll
    for (int j = 0; j < 5; ++j) {
        const int i4 = tid + j * 1024;
        v[j] = row4[(i4 < NVEC) ? i4 : (NVEC - 1)];
    }
    ZSTORE(0);
    ZSTORE(1);
#pragma unroll
    for (int j = 0; j < 4; ++j) hist[tid + j * 1024] = 0;
    BAR();

    unsigned kk[5][4];
#pragma unroll
    for (int j = 0; j < 5; ++j) {
        kk[j][0] = fmap(v[j].x); kk[j][1] = fmap(v[j].y);
        kk[j][2] = fmap(v[j].z); kk[j][3] = fmap(v[j].w);
    }
#pragma unroll
    for (int j = 0; j < 4; ++j) {
#pragma unroll
        for (int e = 0; e < 4; ++e) atomicAdd(&hist[kk[j][e] >> 20], 1u);
    }
    if (tid + 4096 < NVEC) {
#pragma unroll
        for (int e = 0; e < 4; ++e) atomicAdd(&hist[kk[4][e] >> 20], 1u);
    }
    ZSTORE(2);
    BAR();

    // ---- Phase 2: hierarchical threshold-bin pick ----
    unsigned keypref; int w;
    {
#pragma unroll
        for (int j = 0; j < 4; ++j) {
            const int c = wave * 4 + j;
            unsigned x = hist[c * 64 + lane];
#pragma unroll
            for (int off = 32; off; off >>= 1) x += __shfl_down(x, off);
            if (lane == 0) csum[c] = x;
        }
        BAR();
        if (wave == 0) pick64(csum, KSEL, lane, &s_d, &s_w);
        BAR();
        const int chunk = s_d; const int w0 = s_w;
        if (wave == 0) pick64(&hist[chunk * 64], w0, lane, &s_d, &s_w);
        if (tid == 0) s_cnt = 0;
        BAR();
        keypref = (unsigned)(chunk * 64 + s_d);
        w = s_w;
    }
    int shift = 20;
    ZSTORE(3);

    // ---- Phase 3: gather candidate composites from registers ----
    unsigned C;
    for (;;) {
#pragma unroll
        for (int j = 0; j < 5; ++j) {
            const int i4 = tid + j * 1024;
            if (i4 < NVEC) {
#pragma unroll
                for (int e = 0; e < 4; ++e) {
                    const unsigned k = kk[j][e];
                    if ((k >> shift) == keypref) {
                        unsigned p = atomicAdd(&s_cnt, 1u);
                        if (p < CAP) cand[p] = ((u64)k << 32) | (unsigned)~(4 * i4 + e);
                    }
                }
            }
        }
        BAR();
        C = s_cnt;
        if (C <= CAP || shift == 0) break;

        // rare: refine key prefix from reg keys until candidate set fits
        const int nb = (shift >= 12) ? 12 : shift;
        const int nsh = shift - nb;
        for (int i = tid; i < (1 << nb); i += 1024) hist[i] = 0;
        BAR();
#pragma unroll
        for (int j = 0; j < 5; ++j) {
            const int i4 = tid + j * 1024;
            if (i4 < NVEC) {
#pragma unroll
                for (int e = 0; e < 4; ++e) {
                    const unsigned k = kk[j][e];
                    if ((k >> shift) == keypref)
                        atomicAdd(&hist[(k >> nsh) & ((1u << nb) - 1u)], 1u);
                }
            }
        }
        BAR();
        if (wave == 0) select_bin_wave0(hist, 1 << nb, w, &s_d, &s_w, lane);
        if (tid == 0) s_cnt = 0;
        BAR();
        keypref = (keypref << nb) | (unsigned)s_d;
        w = s_w;
        shift = nsh;
    }
    ZSTORE(4);

    // ---- Phase 4: resolve exact threshold ----
    if (C <= CAP) {
        // ranking select: the w-th largest has exactly w-1 greater (all distinct)
        for (int i = tid; i < (int)C; i += 1024) {
            const u64 ci = cand[i];
            int cgt = 0;
            for (int j = 0; j < (int)C; ++j) cgt += (cand[j] > ci) ? 1 : 0;
            if (cgt == w - 1) s_thr = ci;
        }
        BAR();
    } else {
        // unreachable in practice: shift==0 with >CAP exact-duplicate keys.
        if (tid == 0) { s_run = 0; s_cut = 0; }
        BAR();
#pragma unroll 1
        for (int j = 0; j < 5; ++j) {
            const int i4 = tid + j * 1024;
            bool eq[4];
            int cnt4 = 0;
#pragma unroll
            for (int e = 0; e < 4; ++e) {
                eq[e] = (i4 < NVEC) && (kk[j][e] == keypref);
                cnt4 += eq[e] ? 1 : 0;
            }
            unsigned p = (unsigned)cnt4;
#pragma unroll
            for (int off = 1; off < 64; off <<= 1) {
                unsigned t = __shfl_up(p, off);
                if (lane >= off) p += t;
            }
            const unsigned excl = p - (unsigned)cnt4;
            if (lane == 63) s_wc[wave] = (int)p;
            BAR();
            int off0 = s_run + (int)excl;
            for (int x = 0; x < wave; ++x) off0 += s_wc[x];
#pragma unroll
            for (int e = 0; e < 4; ++e) {
                if (eq[e]) { if (off0 == w - 1) s_cut = 4 * i4 + e; ++off0; }
            }
            BAR();
            if (tid == 0) { int t = 0; for (int x = 0; x < 16; ++x) t += s_wc[x]; s_run += t; }
            BAR();
            if (s_run >= w) break;
        }
        if (tid == 0) s_thr = ((u64)keypref << 32) | (unsigned)~s_cut;
        BAR();
    }

    // ---- Phase 5: drain zero-stores, then rewrite own selected elems = 1.0 ----
    const u64 thr = s_thr;
    const unsigned thr_k = (unsigned)(thr >> 32);
    const unsigned thr_l = (unsigned)thr;
    asm volatile("s_waitcnt vmcnt(0)" ::: "memory");
#pragma unroll
    for (int j = 0; j < 5; ++j) {
        const int i4 = tid + j * 1024;
        if (i4 < NVEC) {
            const int n = 4 * i4;
#pragma unroll
            for (int e = 0; e < 4; ++e) {
                const unsigned k = kk[j][e];
                const bool sel = (k > thr_k) || (k == thr_k && (unsigned)~(n + e) >= thr_l);
                if (sel) {
#pragma unroll
                    for (int s = 0; s < NSAMP; ++s)
                        outb[(size_t)s * BN + n + e] = 1.0f;
                }
            }
        }
    }
#undef ZSTORE
}

extern "C" void kernel_launch(void* const* d_in, const int* in_sizes, int n_in,
                              void* d_out, int out_size, void* d_ws, size_t ws_size,
                              hipStream_t stream) {
    const float* logits = (const float*)d_in[0];
    float* out = (float*)d_out;
    (void)d_ws; (void)ws_size;

    topk_fused<<<BATCH, 1024, 0, stream>>>(logits, out);
}